// Round 2
// baseline (746.056 us; speedup 1.0000x reference)
//
#include <hip/hip_runtime.h>
#include <math.h>

typedef __bf16 bf16_t;
typedef __attribute__((ext_vector_type(8))) __bf16 bf16x8;
typedef __attribute__((ext_vector_type(4))) __bf16 bf16x4;
typedef __attribute__((ext_vector_type(4))) float f32x4;

#define NTOK 4096   // B*L tokens
#define DDIM 1024
#define FDIM 4096
#define NEXP 8
#define CAP  4096   // per-expert token capacity (worst case)
#define HROWS (2*NTOK + 128)  // exact pair count + tail slack
#define SPLITK2 4   // gemm2 split-K factor (K=4096 -> 1024 per split)

// async 16B global->LDS. LDS dest must be wave-uniform base + lane*16 — our
// staging mapping (lds off = tid*16B) satisfies this per wave.
#define GLOAD_LDS16(g, l) \
  __builtin_amdgcn_global_load_lds((__attribute__((address_space(1))) void*)(g), \
                                   (__attribute__((address_space(3))) void*)(l), 16, 0, 0)

__device__ __forceinline__ float fast_gelu(float v) {
  // tanh-gelu with exp2-based tanh: tanh(u) = (e^{2u}-1)/(e^{2u}+1)
  float u = 0.7978845608028654f * (v + 0.044715f * v * v * v);
  float uc = fminf(fmaxf(u, -10.f), 10.f);       // avoid inf/inf
  float t = __builtin_amdgcn_exp2f(2.885390081777927f * uc);  // e^{2u}
  float th = (t - 1.f) * __builtin_amdgcn_rcpf(t + 1.f);
  return 0.5f * v * (1.0f + th);
}

// ------------------------------------------------ init: zero out, cvt x, cnts
__global__ __launch_bounds__(256) void init_kernel(const float4* __restrict__ x4,
                                                   float4* __restrict__ out4,
                                                   bf16x4* __restrict__ xbf4,
                                                   int n4, int* __restrict__ cnts) {
  int i = blockIdx.x * 256 + threadIdx.x;
  if (i < n4) {
    out4[i] = make_float4(0.f, 0.f, 0.f, 0.f);
    float4 v = x4[i];
    bf16x4 o;
    o.x = (bf16_t)v.x; o.y = (bf16_t)v.y; o.z = (bf16_t)v.z; o.w = (bf16_t)v.w;
    xbf4[i] = o;
  }
  if (i < NEXP) cnts[i] = 0;
}

// per-expert transpose + fp32->bf16: in (E,R,C) -> out (E,C,R)
// 64x64 tiles; float4 global reads, bf16x8 (16B) global writes.
__global__ __launch_bounds__(256) void transpose_cvt(const float* __restrict__ in,
                                                     bf16_t* __restrict__ outp,
                                                     int R, int C) {
  __shared__ float tile[64][65];  // +1 pad
  int e = blockIdx.z;
  const float* ip = in + (size_t)e * R * C;
  bf16_t* op = outp + (size_t)e * R * C;
  int c0 = blockIdx.x * 64, r0 = blockIdx.y * 64;
  int rr = threadIdx.x >> 4;          // 0..15
  int cc = (threadIdx.x & 15) * 4;    // 0..60
#pragma unroll
  for (int p = 0; p < 4; p++) {
    float4 v = *(const float4*)(ip + (size_t)(r0 + p * 16 + rr) * C + c0 + cc);
    tile[p * 16 + rr][cc + 0] = v.x;
    tile[p * 16 + rr][cc + 1] = v.y;
    tile[p * 16 + rr][cc + 2] = v.z;
    tile[p * 16 + rr][cc + 3] = v.w;
  }
  __syncthreads();
  int c = threadIdx.x >> 3;          // 0..31
  int r8 = (threadIdx.x & 7) * 8;    // 0..56
#pragma unroll
  for (int p = 0; p < 2; p++) {
    int cp = c + p * 32;
    bf16x8 o;
#pragma unroll
    for (int i = 0; i < 8; i++) o[i] = (bf16_t)tile[r8 + i][cp];
    *(bf16x8*)(op + (size_t)(c0 + cp) * R + r0 + r8) = o;
  }
}

// ---------------------------------------------------------------- router
// one wave per token; fp64 logit accumulation so ranking vs numpy ref is stable
__global__ __launch_bounds__(256) void router_kernel(const float* __restrict__ x,
                                                     const float* __restrict__ Wg,
                                                     int* __restrict__ tokL,
                                                     float* __restrict__ gateL,
                                                     int* __restrict__ cnts) {
  int wid = threadIdx.x >> 6, lane = threadIdx.x & 63;
  int n = blockIdx.x * 4 + wid;
  const float* xr = x + (size_t)n * DDIM;
  double acc[NEXP];
#pragma unroll
  for (int e = 0; e < NEXP; e++) acc[e] = 0.0;
  for (int i = 0; i < DDIM / 64; i++) {
    int d = i * 64 + lane;
    float xv = xr[d];
    const float* wr = Wg + (size_t)d * NEXP;
#pragma unroll
    for (int e = 0; e < NEXP; e++) acc[e] += (double)xv * (double)wr[e];
  }
#pragma unroll
  for (int e = 0; e < NEXP; e++) {
    double v = acc[e];
#pragma unroll
    for (int off = 32; off; off >>= 1) v += __shfl_xor(v, off);
    acc[e] = v;
  }
  if (lane == 0) {
    int i1 = -1, i2 = -1;
    double s1 = -1e300, s2 = -1e300;
#pragma unroll
    for (int e = 0; e < NEXP; e++) {
      double v = acc[e];
      if (v > s1) { s2 = s1; i2 = i1; s1 = v; i1 = e; }
      else if (v > s2) { s2 = v; i2 = e; }
    }
    float g1 = 1.0f / (1.0f + expf((float)(-s1)));
    float g2 = 1.0f / (1.0f + expf((float)(-s2)));
    int p1 = atomicAdd(&cnts[i1], 1);
    tokL[i1 * CAP + p1] = n; gateL[i1 * CAP + p1] = g1;
    int p2 = atomicAdd(&cnts[i2], 1);
    tokL[i2 * CAP + p2] = n; gateL[i2 * CAP + p2] = g2;
  }
}

__global__ void offs_kernel(const int* __restrict__ cnts, int* __restrict__ offs) {
  if (threadIdx.x == 0) {
    int s = 0;
    for (int e = 0; e < NEXP; e++) { offs[e] = s; s += cnts[e]; }
    offs[NEXP] = s;
  }
}

// ---------------------------------------------------------------- GEMM1
// H[offs[e]+r, :] = gelu_tanh( x[tok[e][r], :] @ W1[e] + b1[e] ), bf16
// A: gathered xbf rows (M x 1024), B: wt1[e] = W1[e]^T (4096 x 1024, K-contig)
__global__ __launch_bounds__(256) void gemm1_kernel(
    const bf16_t* __restrict__ xbf, const bf16_t* __restrict__ wt1,
    const float* __restrict__ b1, const int* __restrict__ tokL,
    const int* __restrict__ cnts, const int* __restrict__ offs,
    bf16_t* __restrict__ H) {
  const int e = blockIdx.z;
  const int cnt = cnts[e];
  const int m0 = blockIdx.y * 128;
  if (m0 >= cnt) return;
  const int n0 = blockIdx.x * 128;
  const int t = threadIdx.x;

  __shared__ alignas(16) bf16_t As[128 * 32];
  __shared__ alignas(16) bf16_t Bs[128 * 32];

  const int sr = t >> 2;          // staging row 0..63
  const int sc = (t & 3) * 8;     // staging k-chunk
  const int r0 = m0 + sr, r1 = m0 + sr + 64;
  const int tok0 = (r0 < cnt) ? tokL[e * CAP + r0] : 0;
  const int tok1 = (r1 < cnt) ? tokL[e * CAP + r1] : 0;
  const bf16_t* gA0 = xbf + (size_t)tok0 * DDIM + sc;
  const bf16_t* gA1 = xbf + (size_t)tok1 * DDIM + sc;
  const bf16_t* wte = wt1 + (size_t)e * FDIM * DDIM;
  const bf16_t* gB0 = wte + (size_t)(n0 + sr) * DDIM + sc;
  const bf16_t* gB1 = wte + (size_t)(n0 + sr + 64) * DDIM + sc;
  bf16_t* lA0 = As + t * 8; bf16_t* lA1 = As + 2048 + t * 8;
  bf16_t* lB0 = Bs + t * 8; bf16_t* lB1 = Bs + 2048 + t * 8;

  const int lane = t & 63, w = t >> 6;
  const int wm = (w >> 1) * 64, wn = (w & 1) * 64;
  const int lid = lane & 15, quad = lane >> 4;

  f32x4 acc[4][4] = {};
  for (int kk = 0; kk < DDIM; kk += 32) {
    GLOAD_LDS16(gA0 + kk, lA0);
    GLOAD_LDS16(gA1 + kk, lA1);
    GLOAD_LDS16(gB0 + kk, lB0);
    GLOAD_LDS16(gB1 + kk, lB1);
    __syncthreads();
    bf16x8 af[4], bfm[4];
#pragma unroll
    for (int i = 0; i < 4; i++)
      af[i] = *(const bf16x8*)(As + (wm + i * 16 + lid) * 32 + quad * 8);
#pragma unroll
    for (int j = 0; j < 4; j++)
      bfm[j] = *(const bf16x8*)(Bs + (wn + j * 16 + lid) * 32 + quad * 8);
#pragma unroll
    for (int i = 0; i < 4; i++)
#pragma unroll
      for (int j = 0; j < 4; j++)
        acc[i][j] = __builtin_amdgcn_mfma_f32_16x16x32_bf16(af[i], bfm[j], acc[i][j], 0, 0, 0);
    __syncthreads();
  }

  const float* b1e = b1 + (size_t)e * FDIM;
  const int offe = offs[e];
#pragma unroll
  for (int i = 0; i < 4; i++) {
#pragma unroll
    for (int reg = 0; reg < 4; reg++) {
      int pos = m0 + wm + i * 16 + quad * 4 + reg;
      if (pos >= cnt) continue;  // never write pad rows (would race next expert)
      size_t hrow = (size_t)(offe + pos);
#pragma unroll
      for (int j = 0; j < 4; j++) {
        int col = n0 + wn + j * 16 + lid;
        float v = acc[i][j][reg] + b1e[col];
        H[hrow * FDIM + col] = (bf16_t)fast_gelu(v);
      }
    }
  }
}

// ---------------------------------------------------------------- GEMM2
// out[tok,:] += gate * ( H[row,:] @ W2[e] + b2[e] ), split-K over FDIM
// A: H rows (M x 4096), B: wt2[e] = W2[e]^T (1024 x 4096, K-contig)
__global__ __launch_bounds__(256) void gemm2_kernel(
    const bf16_t* __restrict__ H, const bf16_t* __restrict__ wt2,
    const float* __restrict__ b2, const int* __restrict__ tokL,
    const float* __restrict__ gateL, const int* __restrict__ cnts,
    const int* __restrict__ offs, float* __restrict__ out) {
  const int e = blockIdx.z;
  const int cnt = cnts[e];
  const int by = blockIdx.y;
  const int m0 = (by / SPLITK2) * 128;
  const int split = by % SPLITK2;
  if (m0 >= cnt) return;
  const int n0 = blockIdx.x * 128;
  const int t = threadIdx.x;
  const int offe = offs[e];
  const int k0 = split * (FDIM / SPLITK2);

  __shared__ alignas(16) bf16_t As[128 * 32];
  __shared__ alignas(16) bf16_t Bs[128 * 32];

  const int sr = t >> 2;
  const int sc = (t & 3) * 8;
  // pad rows beyond cnt read next expert's H (or slack) — finite, gated to 0
  const bf16_t* gA0 = H + (size_t)(offe + m0 + sr) * FDIM + sc + k0;
  const bf16_t* gA1 = H + (size_t)(offe + m0 + sr + 64) * FDIM + sc + k0;
  const bf16_t* wte = wt2 + (size_t)e * DDIM * FDIM;
  const bf16_t* gB0 = wte + (size_t)(n0 + sr) * FDIM + sc + k0;
  const bf16_t* gB1 = wte + (size_t)(n0 + sr + 64) * FDIM + sc + k0;
  bf16_t* lA0 = As + t * 8; bf16_t* lA1 = As + 2048 + t * 8;
  bf16_t* lB0 = Bs + t * 8; bf16_t* lB1 = Bs + 2048 + t * 8;

  const int lane = t & 63, w = t >> 6;
  const int wm = (w >> 1) * 64, wn = (w & 1) * 64;
  const int lid = lane & 15, quad = lane >> 4;

  f32x4 acc[4][4] = {};
  for (int kk = 0; kk < FDIM / SPLITK2; kk += 32) {
    GLOAD_LDS16(gA0 + kk, lA0);
    GLOAD_LDS16(gA1 + kk, lA1);
    GLOAD_LDS16(gB0 + kk, lB0);
    GLOAD_LDS16(gB1 + kk, lB1);
    __syncthreads();
    bf16x8 af[4], bfm[4];
#pragma unroll
    for (int i = 0; i < 4; i++)
      af[i] = *(const bf16x8*)(As + (wm + i * 16 + lid) * 32 + quad * 8);
#pragma unroll
    for (int j = 0; j < 4; j++)
      bfm[j] = *(const bf16x8*)(Bs + (wn + j * 16 + lid) * 32 + quad * 8);
#pragma unroll
    for (int i = 0; i < 4; i++)
#pragma unroll
      for (int j = 0; j < 4; j++)
        acc[i][j] = __builtin_amdgcn_mfma_f32_16x16x32_bf16(af[i], bfm[j], acc[i][j], 0, 0, 0);
    __syncthreads();
  }

  const float* b2e = b2 + (size_t)e * DDIM;
#pragma unroll
  for (int i = 0; i < 4; i++) {
#pragma unroll
    for (int reg = 0; reg < 4; reg++) {
      int pos = m0 + wm + i * 16 + quad * 4 + reg;
      if (pos >= cnt) continue;
      int tok = tokL[e * CAP + pos];
      float gate = gateL[e * CAP + pos];
#pragma unroll
      for (int j = 0; j < 4; j++) {
        int col = n0 + wn + j * 16 + lid;
        float v = acc[i][j][reg] + ((split == 0) ? b2e[col] : 0.f);
        atomicAdd(out + (size_t)tok * DDIM + col, gate * v);
      }
    }
  }
}

// ---------------------------------------------------------------- launch
extern "C" void kernel_launch(void* const* d_in, const int* in_sizes, int n_in,
                              void* d_out, int out_size, void* d_ws, size_t ws_size,
                              hipStream_t stream) {
  const float* x  = (const float*)d_in[0];
  const float* Wg = (const float*)d_in[1];
  const float* W1 = (const float*)d_in[2];
  const float* b1 = (const float*)d_in[3];
  const float* W2 = (const float*)d_in[4];
  const float* b2 = (const float*)d_in[5];
  float* out = (float*)d_out;

  char* ws = (char*)d_ws;
  size_t off = 0;
  auto alloc = [&](size_t bytes) -> void* {
    void* p = (void*)(ws + off);
    off += (bytes + 255) & ~(size_t)255;
    return p;
  };
  bf16_t* xbf   = (bf16_t*)alloc((size_t)NTOK * DDIM * 2);
  bf16_t* wt1   = (bf16_t*)alloc((size_t)NEXP * FDIM * DDIM * 2);
  bf16_t* wt2   = (bf16_t*)alloc((size_t)NEXP * DDIM * FDIM * 2);
  bf16_t* H     = (bf16_t*)alloc((size_t)HROWS * FDIM * 2);
  int*    tokL  = (int*)alloc((size_t)NEXP * CAP * 4);
  float*  gateL = (float*)alloc((size_t)NEXP * CAP * 4);
  int*    cnts  = (int*)alloc(64);
  int*    offs  = (int*)alloc(64);
  if (off > ws_size) return;  // workspace too small — fail loudly via wrong output

  const int n4 = NTOK * DDIM / 4;
  init_kernel<<<(n4 + 255) / 256, 256, 0, stream>>>((const float4*)x, (float4*)out,
                                                    (bf16x4*)xbf, n4, cnts);
  transpose_cvt<<<dim3(FDIM / 64, DDIM / 64, NEXP), 256, 0, stream>>>(W1, wt1, DDIM, FDIM);
  transpose_cvt<<<dim3(DDIM / 64, FDIM / 64, NEXP), 256, 0, stream>>>(W2, wt2, FDIM, DDIM);
  router_kernel<<<NTOK / 4, 256, 0, stream>>>(x, Wg, tokL, gateL, cnts);
  offs_kernel<<<1, 64, 0, stream>>>(cnts, offs);
  gemm1_kernel<<<dim3(FDIM / 128, CAP / 128, NEXP), 256, 0, stream>>>(
      xbf, wt1, b1, tokL, cnts, offs, H);
  gemm2_kernel<<<dim3(DDIM / 128, (CAP / 128) * SPLITK2, NEXP), 256, 0, stream>>>(
      H, wt2, b2, tokL, gateL, cnts, offs, out);
}

// Round 3
// 703.543 us; speedup vs baseline: 1.0604x; 1.0604x over previous
//
#include <hip/hip_runtime.h>
#include <math.h>

typedef __bf16 bf16_t;
typedef __attribute__((ext_vector_type(8))) __bf16 bf16x8;
typedef __attribute__((ext_vector_type(4))) __bf16 bf16x4;
typedef __attribute__((ext_vector_type(4))) float f32x4;

#define NTOK 4096   // B*L tokens
#define DDIM 1024
#define FDIM 4096
#define NEXP 8
#define CAP  4096   // per-expert token capacity (worst case)
#define HROWS (2*NTOK + 128)  // exact pair count + tail slack for A-tile overreads
#define NPAIR (2*NTOK)

// async 16B global->LDS. LDS dest must be wave-uniform base + lane*16 — our
// staging mapping (lds off = tid*16B) satisfies this per wave.
#define GLOAD_LDS16(g, l) \
  __builtin_amdgcn_global_load_lds((__attribute__((address_space(1))) void*)(g), \
                                   (__attribute__((address_space(3))) void*)(l), 16, 0, 0)

__device__ __forceinline__ float fast_gelu(float v) {
  // tanh-gelu with exp2-based tanh: tanh(u) = (e^{2u}-1)/(e^{2u}+1)
  float u = 0.7978845608028654f * (v + 0.044715f * v * v * v);
  float uc = fminf(fmaxf(u, -10.f), 10.f);       // avoid inf/inf
  float t = __builtin_amdgcn_exp2f(2.885390081777927f * uc);  // e^{2u}
  float th = (t - 1.f) * __builtin_amdgcn_rcpf(t + 1.f);
  return 0.5f * v * (1.0f + th);
}

// ------------------------------------------------ init: cvt x -> bf16, zero cnts
__global__ __launch_bounds__(256) void init_kernel(const float4* __restrict__ x4,
                                                   bf16x4* __restrict__ xbf4,
                                                   int n4, int* __restrict__ cnts) {
  int i = blockIdx.x * 256 + threadIdx.x;
  if (i < n4) {
    float4 v = x4[i];
    bf16x4 o;
    o.x = (bf16_t)v.x; o.y = (bf16_t)v.y; o.z = (bf16_t)v.z; o.w = (bf16_t)v.w;
    xbf4[i] = o;
  }
  if (i < NEXP) cnts[i] = 0;
}

// per-expert transpose + fp32->bf16: in (E,R,C) -> out (E,C,R)
// 64x64 tiles; float4 global reads, bf16x8 (16B) global writes.
__global__ __launch_bounds__(256) void transpose_cvt(const float* __restrict__ in,
                                                     bf16_t* __restrict__ outp,
                                                     int R, int C) {
  __shared__ float tile[64][65];  // +1 pad
  int e = blockIdx.z;
  const float* ip = in + (size_t)e * R * C;
  bf16_t* op = outp + (size_t)e * R * C;
  int c0 = blockIdx.x * 64, r0 = blockIdx.y * 64;
  int rr = threadIdx.x >> 4;          // 0..15
  int cc = (threadIdx.x & 15) * 4;    // 0..60
#pragma unroll
  for (int p = 0; p < 4; p++) {
    float4 v = *(const float4*)(ip + (size_t)(r0 + p * 16 + rr) * C + c0 + cc);
    tile[p * 16 + rr][cc + 0] = v.x;
    tile[p * 16 + rr][cc + 1] = v.y;
    tile[p * 16 + rr][cc + 2] = v.z;
    tile[p * 16 + rr][cc + 3] = v.w;
  }
  __syncthreads();
  int c = threadIdx.x >> 3;          // 0..31
  int r8 = (threadIdx.x & 7) * 8;    // 0..56
#pragma unroll
  for (int p = 0; p < 2; p++) {
    int cp = c + p * 32;
    bf16x8 o;
#pragma unroll
    for (int i = 0; i < 8; i++) o[i] = (bf16_t)tile[r8 + i][cp];
    *(bf16x8*)(op + (size_t)(c0 + cp) * R + r0 + r8) = o;
  }
}

// ---------------------------------------------------------------- router
// one wave per token; fp64 logit accumulation so ranking vs numpy ref is stable
__global__ __launch_bounds__(256) void router_kernel(const float* __restrict__ x,
                                                     const float* __restrict__ Wg,
                                                     int* __restrict__ tokL,
                                                     int* __restrict__ cnts,
                                                     int* __restrict__ pairE,
                                                     int* __restrict__ pairS,
                                                     float* __restrict__ pairG) {
  int wid = threadIdx.x >> 6, lane = threadIdx.x & 63;
  int n = blockIdx.x * 4 + wid;
  const float* xr = x + (size_t)n * DDIM;
  double acc[NEXP];
#pragma unroll
  for (int e = 0; e < NEXP; e++) acc[e] = 0.0;
  for (int i = 0; i < DDIM / 64; i++) {
    int d = i * 64 + lane;
    float xv = xr[d];
    const float* wr = Wg + (size_t)d * NEXP;
#pragma unroll
    for (int e = 0; e < NEXP; e++) acc[e] += (double)xv * (double)wr[e];
  }
#pragma unroll
  for (int e = 0; e < NEXP; e++) {
    double v = acc[e];
#pragma unroll
    for (int off = 32; off; off >>= 1) v += __shfl_xor(v, off);
    acc[e] = v;
  }
  if (lane == 0) {
    int i1 = -1, i2 = -1;
    double s1 = -1e300, s2 = -1e300;
#pragma unroll
    for (int e = 0; e < NEXP; e++) {
      double v = acc[e];
      if (v > s1) { s2 = s1; i2 = i1; s1 = v; i1 = e; }
      else if (v > s2) { s2 = v; i2 = e; }
    }
    float g1 = 1.0f / (1.0f + expf((float)(-s1)));
    float g2 = 1.0f / (1.0f + expf((float)(-s2)));
    int p1 = atomicAdd(&cnts[i1], 1);
    tokL[i1 * CAP + p1] = n;
    int p2 = atomicAdd(&cnts[i2], 1);
    tokL[i2 * CAP + p2] = n;
    pairE[2 * n] = i1; pairS[2 * n] = p1; pairG[2 * n] = g1;
    pairE[2 * n + 1] = i2; pairS[2 * n + 1] = p2; pairG[2 * n + 1] = g2;
  }
}

__global__ void offs_kernel(const int* __restrict__ cnts, int* __restrict__ offs) {
  if (threadIdx.x == 0) {
    int s = 0;
    for (int e = 0; e < NEXP; e++) { offs[e] = s; s += cnts[e]; }
    offs[NEXP] = s;
  }
}

// ---------------------------------------------------------------- GEMM1
// H[offs[e]+r, :] = gelu_tanh( x[tok[e][r], :] @ W1[e] + b1[e] ), bf16
// A: gathered xbf rows (M x 1024), B: wt1[e] = W1[e]^T (4096 x 1024, K-contig)
__global__ __launch_bounds__(256) void gemm1_kernel(
    const bf16_t* __restrict__ xbf, const bf16_t* __restrict__ wt1,
    const float* __restrict__ b1, const int* __restrict__ tokL,
    const int* __restrict__ cnts, const int* __restrict__ offs,
    bf16_t* __restrict__ H) {
  const int e = blockIdx.z;
  const int cnt = cnts[e];
  const int m0 = blockIdx.y * 128;
  if (m0 >= cnt) return;
  const int n0 = blockIdx.x * 128;
  const int t = threadIdx.x;

  __shared__ alignas(16) bf16_t As[128 * 32];
  __shared__ alignas(16) bf16_t Bs[128 * 32];

  const int sr = t >> 2;          // staging row 0..63
  const int sc = (t & 3) * 8;     // staging k-chunk
  const int r0 = m0 + sr, r1 = m0 + sr + 64;
  const int tok0 = (r0 < cnt) ? tokL[e * CAP + r0] : 0;
  const int tok1 = (r1 < cnt) ? tokL[e * CAP + r1] : 0;
  const bf16_t* gA0 = xbf + (size_t)tok0 * DDIM + sc;
  const bf16_t* gA1 = xbf + (size_t)tok1 * DDIM + sc;
  const bf16_t* wte = wt1 + (size_t)e * FDIM * DDIM;
  const bf16_t* gB0 = wte + (size_t)(n0 + sr) * DDIM + sc;
  const bf16_t* gB1 = wte + (size_t)(n0 + sr + 64) * DDIM + sc;
  bf16_t* lA0 = As + t * 8; bf16_t* lA1 = As + 2048 + t * 8;
  bf16_t* lB0 = Bs + t * 8; bf16_t* lB1 = Bs + 2048 + t * 8;

  const int lane = t & 63, w = t >> 6;
  const int wm = (w >> 1) * 64, wn = (w & 1) * 64;
  const int lid = lane & 15, quad = lane >> 4;

  f32x4 acc[4][4] = {};
  for (int kk = 0; kk < DDIM; kk += 32) {
    GLOAD_LDS16(gA0 + kk, lA0);
    GLOAD_LDS16(gA1 + kk, lA1);
    GLOAD_LDS16(gB0 + kk, lB0);
    GLOAD_LDS16(gB1 + kk, lB1);
    __syncthreads();
    bf16x8 af[4], bfm[4];
#pragma unroll
    for (int i = 0; i < 4; i++)
      af[i] = *(const bf16x8*)(As + (wm + i * 16 + lid) * 32 + quad * 8);
#pragma unroll
    for (int j = 0; j < 4; j++)
      bfm[j] = *(const bf16x8*)(Bs + (wn + j * 16 + lid) * 32 + quad * 8);
#pragma unroll
    for (int i = 0; i < 4; i++)
#pragma unroll
      for (int j = 0; j < 4; j++)
        acc[i][j] = __builtin_amdgcn_mfma_f32_16x16x32_bf16(af[i], bfm[j], acc[i][j], 0, 0, 0);
    __syncthreads();
  }

  const float* b1e = b1 + (size_t)e * FDIM;
  const int offe = offs[e];
#pragma unroll
  for (int i = 0; i < 4; i++) {
#pragma unroll
    for (int reg = 0; reg < 4; reg++) {
      int pos = m0 + wm + i * 16 + quad * 4 + reg;
      if (pos >= cnt) continue;  // never write pad rows (would race next expert)
      size_t hrow = (size_t)(offe + pos);
#pragma unroll
      for (int j = 0; j < 4; j++) {
        int col = n0 + wn + j * 16 + lid;
        float v = acc[i][j][reg] + b1e[col];
        H[hrow * FDIM + col] = (bf16_t)fast_gelu(v);
      }
    }
  }
}

// ---------------------------------------------------------------- GEMM2
// Y{0,1}[offs[e]+r, :] = H[row, k-half] @ W2[e][k-half]  (split-K=2, no bias/gate)
// A: H rows (M x 4096), B: wt2[e] = W2[e]^T (1024 x 4096, K-contig)
__global__ __launch_bounds__(256) void gemm2_kernel(
    const bf16_t* __restrict__ H, const bf16_t* __restrict__ wt2,
    const int* __restrict__ cnts, const int* __restrict__ offs,
    float* __restrict__ Y0, float* __restrict__ Y1) {
  const int e = blockIdx.z;
  const int cnt = cnts[e];
  const int by = blockIdx.y;
  const int m0 = (by >> 1) * 128;
  const int split = by & 1;
  if (m0 >= cnt) return;
  const int n0 = blockIdx.x * 128;
  const int t = threadIdx.x;
  const int offe = offs[e];
  const int k0 = split * (FDIM / 2);

  __shared__ alignas(16) bf16_t As[128 * 32];
  __shared__ alignas(16) bf16_t Bs[128 * 32];

  const int sr = t >> 2;
  const int sc = (t & 3) * 8;
  // pad rows beyond cnt read next expert's H (or slack) — finite, never combined
  const bf16_t* gA0 = H + (size_t)(offe + m0 + sr) * FDIM + sc + k0;
  const bf16_t* gA1 = H + (size_t)(offe + m0 + sr + 64) * FDIM + sc + k0;
  const bf16_t* wte = wt2 + (size_t)e * DDIM * FDIM;
  const bf16_t* gB0 = wte + (size_t)(n0 + sr) * FDIM + sc + k0;
  const bf16_t* gB1 = wte + (size_t)(n0 + sr + 64) * FDIM + sc + k0;
  bf16_t* lA0 = As + t * 8; bf16_t* lA1 = As + 2048 + t * 8;
  bf16_t* lB0 = Bs + t * 8; bf16_t* lB1 = Bs + 2048 + t * 8;

  const int lane = t & 63, w = t >> 6;
  const int wm = (w >> 1) * 64, wn = (w & 1) * 64;
  const int lid = lane & 15, quad = lane >> 4;

  f32x4 acc[4][4] = {};
  for (int kk = 0; kk < FDIM / 2; kk += 32) {
    GLOAD_LDS16(gA0 + kk, lA0);
    GLOAD_LDS16(gA1 + kk, lA1);
    GLOAD_LDS16(gB0 + kk, lB0);
    GLOAD_LDS16(gB1 + kk, lB1);
    __syncthreads();
    bf16x8 af[4], bfm[4];
#pragma unroll
    for (int i = 0; i < 4; i++)
      af[i] = *(const bf16x8*)(As + (wm + i * 16 + lid) * 32 + quad * 8);
#pragma unroll
    for (int j = 0; j < 4; j++)
      bfm[j] = *(const bf16x8*)(Bs + (wn + j * 16 + lid) * 32 + quad * 8);
#pragma unroll
    for (int i = 0; i < 4; i++)
#pragma unroll
      for (int j = 0; j < 4; j++)
        acc[i][j] = __builtin_amdgcn_mfma_f32_16x16x32_bf16(af[i], bfm[j], acc[i][j], 0, 0, 0);
    __syncthreads();
  }

  float* Ye = split ? Y1 : Y0;
#pragma unroll
  for (int i = 0; i < 4; i++) {
#pragma unroll
    for (int reg = 0; reg < 4; reg++) {
      int pos = m0 + wm + i * 16 + quad * 4 + reg;
      if (pos >= cnt) continue;
      float* yrow = Ye + (size_t)(offe + pos) * DDIM;
#pragma unroll
      for (int j = 0; j < 4; j++) {
        int col = n0 + wn + j * 16 + lid;
        yrow[col] = acc[i][j][reg];
      }
    }
  }
}

// ---------------------------------------------------------------- combine
// out[n,:] = g1*(Y0[r1]+Y1[r1]+b2[e1]) + g2*(Y0[r2]+Y1[r2]+b2[e2])
__global__ __launch_bounds__(256) void combine_kernel(
    const float* __restrict__ Y0, const float* __restrict__ Y1,
    const float* __restrict__ b2, const int* __restrict__ pairE,
    const int* __restrict__ pairS, const float* __restrict__ pairG,
    const int* __restrict__ offs, float4* __restrict__ out4) {
  const int n = blockIdx.x;
  const int e1 = pairE[2 * n], e2 = pairE[2 * n + 1];
  const int r1 = offs[e1] + pairS[2 * n];
  const int r2 = offs[e2] + pairS[2 * n + 1];
  const float g1 = pairG[2 * n], g2 = pairG[2 * n + 1];
  const int t = threadIdx.x;  // 256 threads x float4 = 1024 floats
  const float4* ya0 = (const float4*)(Y0 + (size_t)r1 * DDIM);
  const float4* ya1 = (const float4*)(Y1 + (size_t)r1 * DDIM);
  const float4* yb0 = (const float4*)(Y0 + (size_t)r2 * DDIM);
  const float4* yb1 = (const float4*)(Y1 + (size_t)r2 * DDIM);
  const float4* ba = (const float4*)(b2 + (size_t)e1 * DDIM);
  const float4* bb = (const float4*)(b2 + (size_t)e2 * DDIM);
  float4 a0 = ya0[t], a1 = ya1[t], c0 = yb0[t], c1 = yb1[t];
  float4 pa = ba[t], pb = bb[t];
  float4 o;
  o.x = g1 * (a0.x + a1.x + pa.x) + g2 * (c0.x + c1.x + pb.x);
  o.y = g1 * (a0.y + a1.y + pa.y) + g2 * (c0.y + c1.y + pb.y);
  o.z = g1 * (a0.z + a1.z + pa.z) + g2 * (c0.z + c1.z + pb.z);
  o.w = g1 * (a0.w + a1.w + pa.w) + g2 * (c0.w + c1.w + pb.w);
  out4[(size_t)n * (DDIM / 4) + t] = o;
}

// ---------------------------------------------------------------- launch
extern "C" void kernel_launch(void* const* d_in, const int* in_sizes, int n_in,
                              void* d_out, int out_size, void* d_ws, size_t ws_size,
                              hipStream_t stream) {
  const float* x  = (const float*)d_in[0];
  const float* Wg = (const float*)d_in[1];
  const float* W1 = (const float*)d_in[2];
  const float* b1 = (const float*)d_in[3];
  const float* W2 = (const float*)d_in[4];
  const float* b2 = (const float*)d_in[5];
  float* out = (float*)d_out;

  char* ws = (char*)d_ws;
  size_t off = 0;
  auto alloc = [&](size_t bytes) -> void* {
    void* p = (void*)(ws + off);
    off += (bytes + 255) & ~(size_t)255;
    return p;
  };
  bf16_t* xbf   = (bf16_t*)alloc((size_t)NTOK * DDIM * 2);
  bf16_t* wt1   = (bf16_t*)alloc((size_t)NEXP * FDIM * DDIM * 2);  // dead after gemm1
  bf16_t* wt2   = (bf16_t*)alloc((size_t)NEXP * DDIM * FDIM * 2);
  bf16_t* H     = (bf16_t*)alloc((size_t)HROWS * FDIM * 2);
  int*    tokL  = (int*)alloc((size_t)NEXP * CAP * 4);
  int*    pairE = (int*)alloc((size_t)NPAIR * 4);
  int*    pairS = (int*)alloc((size_t)NPAIR * 4);
  float*  pairG = (float*)alloc((size_t)NPAIR * 4);
  int*    cnts  = (int*)alloc(64);
  int*    offs  = (int*)alloc(64);
  if (off > ws_size) return;  // workspace too small — fail loudly via wrong output

  // Y0/Y1 alias wt1's 64 MiB (wt1 is consumed by gemm1, which completes before
  // gemm2 starts on the same stream). 2 x 8192 x 1024 fp32 = exactly 64 MiB.
  float* Y0 = (float*)wt1;
  float* Y1 = Y0 + (size_t)NPAIR * DDIM / 2 * 2;  // + 8192*1024 floats... see below
  Y1 = Y0 + (size_t)8192 * DDIM;

  const int n4 = NTOK * DDIM / 4;
  init_kernel<<<(n4 + 255) / 256, 256, 0, stream>>>((const float4*)x, (bf16x4*)xbf,
                                                    n4, cnts);
  transpose_cvt<<<dim3(FDIM / 64, DDIM / 64, NEXP), 256, 0, stream>>>(W1, wt1, DDIM, FDIM);
  transpose_cvt<<<dim3(DDIM / 64, FDIM / 64, NEXP), 256, 0, stream>>>(W2, wt2, FDIM, DDIM);
  router_kernel<<<NTOK / 4, 256, 0, stream>>>(x, Wg, tokL, cnts, pairE, pairS, pairG);
  offs_kernel<<<1, 64, 0, stream>>>(cnts, offs);
  gemm1_kernel<<<dim3(FDIM / 128, CAP / 128, NEXP), 256, 0, stream>>>(
      xbf, wt1, b1, tokL, cnts, offs, H);
  gemm2_kernel<<<dim3(DDIM / 128, (CAP / 128) * 2, NEXP), 256, 0, stream>>>(
      H, wt2, cnts, offs, Y0, Y1);
  combine_kernel<<<NTOK, 256, 0, stream>>>(Y0, Y1, b2, pairE, pairS, pairG, offs,
                                           (float4*)out);
}

// Round 4
// 697.238 us; speedup vs baseline: 1.0700x; 1.0090x over previous
//
#include <hip/hip_runtime.h>
#include <math.h>

typedef __bf16 bf16_t;
typedef __attribute__((ext_vector_type(8))) __bf16 bf16x8;
typedef __attribute__((ext_vector_type(4))) __bf16 bf16x4;
typedef __attribute__((ext_vector_type(4))) float f32x4;

#define NTOK 4096   // B*L tokens
#define DDIM 1024
#define FDIM 4096
#define NEXP 8
#define CAP  4096   // per-expert token capacity (worst case)
#define HROWS (2*NTOK + 128)  // pair count + slack for gemm2 A-tile overreads
#define NPAIR (2*NTOK)
#define MAXB 72     // max live m-blocks: floor(8192/128)+7 = 71

// async 16B global->LDS. LDS dest must be wave-uniform base + lane*16.
#define GLOAD_LDS16(g, l) \
  __builtin_amdgcn_global_load_lds((__attribute__((address_space(1))) void*)(g), \
                                   (__attribute__((address_space(3))) void*)(l), 16, 0, 0)

__device__ __forceinline__ float fast_gelu(float v) {
  float u = 0.7978845608028654f * (v + 0.044715f * v * v * v);
  float uc = fminf(fmaxf(u, -10.f), 10.f);
  float t = __builtin_amdgcn_exp2f(2.885390081777927f * uc);  // e^{2u}
  float th = (t - 1.f) * __builtin_amdgcn_rcpf(t + 1.f);
  return 0.5f * v * (1.0f + th);
}

// ---------------------------------------------------------------- prep
// One kernel, 1D grid partitioned: [0,4096) W1-T | [4096,8192) W2-T |
// [8192,12288) x->bf16 | [12288,13312) router. All partitions independent.
// Transpose: 128r x 64c tile; LDS stored transposed at pitch 129 (<=2-way bank
// aliasing on stores = free); reads are 256B segments, writes 4x16B/lane.
__device__ __forceinline__ void tile_transpose(const float* __restrict__ ip,
                                               bf16_t* __restrict__ op,
                                               int R, int C, int r0, int c0,
                                               float* tileT, int t) {
#pragma unroll
  for (int it = 0; it < 8; it++) {
    int idx = it * 256 + t;
    int row = idx >> 4;
    int c4 = (idx & 15) << 2;
    float4 v = *(const float4*)(ip + (size_t)(r0 + row) * C + c0 + c4);
    tileT[(c4 + 0) * 129 + row] = v.x;
    tileT[(c4 + 1) * 129 + row] = v.y;
    tileT[(c4 + 2) * 129 + row] = v.z;
    tileT[(c4 + 3) * 129 + row] = v.w;
  }
  __syncthreads();
  int c = t >> 2;
  int rs = (t & 3) * 32;
  const float* src = tileT + c * 129 + rs;
  bf16_t* dst = op + (size_t)(c0 + c) * R + r0 + rs;
#pragma unroll
  for (int seg = 0; seg < 4; seg++) {
    bf16x8 o;
#pragma unroll
    for (int i = 0; i < 8; i++) o[i] = (bf16_t)src[seg * 8 + i];
    *(bf16x8*)(dst + seg * 8) = o;
  }
}

__global__ __launch_bounds__(256) void prep_kernel(
    const float* __restrict__ W1, const float* __restrict__ W2,
    const float* __restrict__ x, const float* __restrict__ Wg,
    bf16_t* __restrict__ wt1, bf16_t* __restrict__ wt2,
    bf16_t* __restrict__ xbf, int* __restrict__ tokL, int* __restrict__ cnts,
    int* __restrict__ pairE, int* __restrict__ pairS, float* __restrict__ pairG) {
  __shared__ float tileT[64 * 129];
  const int b = blockIdx.x;
  const int t = threadIdx.x;
  if (b < 4096) {  // W1 (E,1024,4096) -> wt1 (E,4096,1024)
    int e = b >> 9, ti = b & 511;
    int r0 = (ti & 7) * 128, c0 = (ti >> 3) * 64;
    tile_transpose(W1 + (size_t)e * DDIM * FDIM, wt1 + (size_t)e * DDIM * FDIM,
                   DDIM, FDIM, r0, c0, tileT, t);
  } else if (b < 8192) {  // W2 (E,4096,1024) -> wt2 (E,1024,4096)
    int b0 = b - 4096;
    int e = b0 >> 9, ti = b0 & 511;
    int r0 = (ti & 31) * 128, c0 = (ti >> 5) * 64;
    tile_transpose(W2 + (size_t)e * FDIM * DDIM, wt2 + (size_t)e * FDIM * DDIM,
                   FDIM, DDIM, r0, c0, tileT, t);
  } else if (b < 12288) {  // x -> bf16 (exactly covers NTOK*DDIM/4 elements)
    int i = (b - 8192) * 256 + t;
    float4 v = ((const float4*)x)[i];
    bf16x4 o;
    o.x = (bf16_t)v.x; o.y = (bf16_t)v.y; o.z = (bf16_t)v.z; o.w = (bf16_t)v.w;
    ((bf16x4*)xbf)[i] = o;
  } else {  // router: 4 tokens/block, one wave/token, fp64 logits
    int b0 = b - 12288;
    int wid = t >> 6, lane = t & 63;
    int n = b0 * 4 + wid;
    const float* xr = x + (size_t)n * DDIM;
    double acc[NEXP];
#pragma unroll
    for (int e = 0; e < NEXP; e++) acc[e] = 0.0;
    for (int i = 0; i < DDIM / 64; i++) {
      int d = i * 64 + lane;
      float xv = xr[d];
      const float* wr = Wg + (size_t)d * NEXP;
#pragma unroll
      for (int e = 0; e < NEXP; e++) acc[e] += (double)xv * (double)wr[e];
    }
#pragma unroll
    for (int e = 0; e < NEXP; e++) {
      double v = acc[e];
#pragma unroll
      for (int off = 32; off; off >>= 1) v += __shfl_xor(v, off);
      acc[e] = v;
    }
    if (lane == 0) {
      int i1 = -1, i2 = -1;
      double s1 = -1e300, s2 = -1e300;
#pragma unroll
      for (int e = 0; e < NEXP; e++) {
        double v = acc[e];
        if (v > s1) { s2 = s1; i2 = i1; s1 = v; i1 = e; }
        else if (v > s2) { s2 = v; i2 = e; }
      }
      float g1 = 1.0f / (1.0f + expf((float)(-s1)));
      float g2 = 1.0f / (1.0f + expf((float)(-s2)));
      int p1 = atomicAdd(&cnts[i1], 1);
      tokL[i1 * CAP + p1] = n;
      int p2 = atomicAdd(&cnts[i2], 1);
      tokL[i2 * CAP + p2] = n;
      pairE[2 * n] = i1; pairS[2 * n] = p1; pairG[2 * n] = g1;
      pairE[2 * n + 1] = i2; pairS[2 * n + 1] = p2; pairG[2 * n + 1] = g2;
    }
  }
}

// offsets + flat m-block table (serial, trivial size)
__global__ void offs_kernel(const int* __restrict__ cnts, int* __restrict__ offs,
                            int* __restrict__ blkE, int* __restrict__ blkS) {
  if (threadIdx.x == 0) {
    int s = 0, nb = 0;
    for (int e = 0; e < NEXP; e++) {
      offs[e] = s;
      for (int st = 0; st < cnts[e]; st += 128) { blkE[nb] = e; blkS[nb] = st; nb++; }
      s += cnts[e];
    }
    offs[NEXP] = s;
    for (; nb < MAXB; nb++) { blkE[nb] = NEXP; blkS[nb] = 0; }
  }
}

// ---------------------------------------------------------------- GEMM1
// H[offs[e]+r, :] = gelu( x[tok[e][r], :] @ W1[e] + b1[e] ), bf16
__global__ __launch_bounds__(256) void gemm1_kernel(
    const bf16_t* __restrict__ xbf, const bf16_t* __restrict__ wt1,
    const float* __restrict__ b1, const int* __restrict__ tokL,
    const int* __restrict__ cnts, const int* __restrict__ offs,
    const int* __restrict__ blkE, const int* __restrict__ blkS,
    bf16_t* __restrict__ H) {
  const int e = blkE[blockIdx.y];
  if (e >= NEXP) return;
  const int m0 = blkS[blockIdx.y];
  const int cnt = cnts[e];
  const int n0 = blockIdx.x * 128;
  const int t = threadIdx.x;

  __shared__ alignas(16) bf16_t As[128 * 32];
  __shared__ alignas(16) bf16_t Bs[128 * 32];

  const int sr = t >> 2;
  const int sc = (t & 3) * 8;
  const int r0 = m0 + sr, r1 = m0 + sr + 64;
  const int tok0 = (r0 < cnt) ? tokL[e * CAP + r0] : 0;
  const int tok1 = (r1 < cnt) ? tokL[e * CAP + r1] : 0;
  const bf16_t* gA0 = xbf + (size_t)tok0 * DDIM + sc;
  const bf16_t* gA1 = xbf + (size_t)tok1 * DDIM + sc;
  const bf16_t* wte = wt1 + (size_t)e * FDIM * DDIM;
  const bf16_t* gB0 = wte + (size_t)(n0 + sr) * DDIM + sc;
  const bf16_t* gB1 = wte + (size_t)(n0 + sr + 64) * DDIM + sc;
  bf16_t* lA0 = As + t * 8; bf16_t* lA1 = As + 2048 + t * 8;
  bf16_t* lB0 = Bs + t * 8; bf16_t* lB1 = Bs + 2048 + t * 8;

  const int lane = t & 63, w = t >> 6;
  const int wm = (w >> 1) * 64, wn = (w & 1) * 64;
  const int lid = lane & 15, quad = lane >> 4;

  f32x4 acc[4][4] = {};
  for (int kk = 0; kk < DDIM; kk += 32) {
    GLOAD_LDS16(gA0 + kk, lA0);
    GLOAD_LDS16(gA1 + kk, lA1);
    GLOAD_LDS16(gB0 + kk, lB0);
    GLOAD_LDS16(gB1 + kk, lB1);
    __syncthreads();
    bf16x8 af[4], bfm[4];
#pragma unroll
    for (int i = 0; i < 4; i++)
      af[i] = *(const bf16x8*)(As + (wm + i * 16 + lid) * 32 + quad * 8);
#pragma unroll
    for (int j = 0; j < 4; j++)
      bfm[j] = *(const bf16x8*)(Bs + (wn + j * 16 + lid) * 32 + quad * 8);
#pragma unroll
    for (int i = 0; i < 4; i++)
#pragma unroll
      for (int j = 0; j < 4; j++)
        acc[i][j] = __builtin_amdgcn_mfma_f32_16x16x32_bf16(af[i], bfm[j], acc[i][j], 0, 0, 0);
    __syncthreads();
  }

  const float* b1e = b1 + (size_t)e * FDIM;
  const int offe = offs[e];
#pragma unroll
  for (int i = 0; i < 4; i++) {
#pragma unroll
    for (int reg = 0; reg < 4; reg++) {
      int pos = m0 + wm + i * 16 + quad * 4 + reg;
      if (pos >= cnt) continue;  // never write pad rows
      size_t hrow = (size_t)(offe + pos);
#pragma unroll
      for (int j = 0; j < 4; j++) {
        int col = n0 + wn + j * 16 + lid;
        float v = acc[i][j][reg] + b1e[col];
        H[hrow * FDIM + col] = (bf16_t)fast_gelu(v);
      }
    }
  }
}

// ---------------------------------------------------------------- GEMM2
// Y{0,1}[offs[e]+r, :] = H[row, k-half] @ W2[e][k-half]  (split-K=2)
__global__ __launch_bounds__(256) void gemm2_kernel(
    const bf16_t* __restrict__ H, const bf16_t* __restrict__ wt2,
    const int* __restrict__ cnts, const int* __restrict__ offs,
    const int* __restrict__ blkE, const int* __restrict__ blkS,
    float* __restrict__ Y0, float* __restrict__ Y1) {
  const int bi = blockIdx.y >> 1;
  const int split = blockIdx.y & 1;
  const int e = blkE[bi];
  if (e >= NEXP) return;
  const int m0 = blkS[bi];
  const int cnt = cnts[e];
  const int n0 = blockIdx.x * 128;
  const int t = threadIdx.x;
  const int offe = offs[e];
  const int k0 = split * (FDIM / 2);

  __shared__ alignas(16) bf16_t As[128 * 32];
  __shared__ alignas(16) bf16_t Bs[128 * 32];

  const int sr = t >> 2;
  const int sc = (t & 3) * 8;
  const bf16_t* gA0 = H + (size_t)(offe + m0 + sr) * FDIM + sc + k0;
  const bf16_t* gA1 = H + (size_t)(offe + m0 + sr + 64) * FDIM + sc + k0;
  const bf16_t* wte = wt2 + (size_t)e * DDIM * FDIM;
  const bf16_t* gB0 = wte + (size_t)(n0 + sr) * FDIM + sc + k0;
  const bf16_t* gB1 = wte + (size_t)(n0 + sr + 64) * FDIM + sc + k0;
  bf16_t* lA0 = As + t * 8; bf16_t* lA1 = As + 2048 + t * 8;
  bf16_t* lB0 = Bs + t * 8; bf16_t* lB1 = Bs + 2048 + t * 8;

  const int lane = t & 63, w = t >> 6;
  const int wm = (w >> 1) * 64, wn = (w & 1) * 64;
  const int lid = lane & 15, quad = lane >> 4;

  f32x4 acc[4][4] = {};
  for (int kk = 0; kk < FDIM / 2; kk += 32) {
    GLOAD_LDS16(gA0 + kk, lA0);
    GLOAD_LDS16(gA1 + kk, lA1);
    GLOAD_LDS16(gB0 + kk, lB0);
    GLOAD_LDS16(gB1 + kk, lB1);
    __syncthreads();
    bf16x8 af[4], bfm[4];
#pragma unroll
    for (int i = 0; i < 4; i++)
      af[i] = *(const bf16x8*)(As + (wm + i * 16 + lid) * 32 + quad * 8);
#pragma unroll
    for (int j = 0; j < 4; j++)
      bfm[j] = *(const bf16x8*)(Bs + (wn + j * 16 + lid) * 32 + quad * 8);
#pragma unroll
    for (int i = 0; i < 4; i++)
#pragma unroll
      for (int j = 0; j < 4; j++)
        acc[i][j] = __builtin_amdgcn_mfma_f32_16x16x32_bf16(af[i], bfm[j], acc[i][j], 0, 0, 0);
    __syncthreads();
  }

  float* Ye = split ? Y1 : Y0;
#pragma unroll
  for (int i = 0; i < 4; i++) {
#pragma unroll
    for (int reg = 0; reg < 4; reg++) {
      int pos = m0 + wm + i * 16 + quad * 4 + reg;
      if (pos >= cnt) continue;
      float* yrow = Ye + (size_t)(offe + pos) * DDIM;
#pragma unroll
      for (int j = 0; j < 4; j++) {
        int col = n0 + wn + j * 16 + lid;
        yrow[col] = acc[i][j][reg];
      }
    }
  }
}

// ---------------------------------------------------------------- combine
__global__ __launch_bounds__(256) void combine_kernel(
    const float* __restrict__ Y0, const float* __restrict__ Y1,
    const float* __restrict__ b2, const int* __restrict__ pairE,
    const int* __restrict__ pairS, const float* __restrict__ pairG,
    const int* __restrict__ offs, float4* __restrict__ out4) {
  const int n = blockIdx.x;
  const int e1 = pairE[2 * n], e2 = pairE[2 * n + 1];
  const int r1 = offs[e1] + pairS[2 * n];
  const int r2 = offs[e2] + pairS[2 * n + 1];
  const float g1 = pairG[2 * n], g2 = pairG[2 * n + 1];
  const int t = threadIdx.x;
  const float4* ya0 = (const float4*)(Y0 + (size_t)r1 * DDIM);
  const float4* ya1 = (const float4*)(Y1 + (size_t)r1 * DDIM);
  const float4* yb0 = (const float4*)(Y0 + (size_t)r2 * DDIM);
  const float4* yb1 = (const float4*)(Y1 + (size_t)r2 * DDIM);
  const float4* ba = (const float4*)(b2 + (size_t)e1 * DDIM);
  const float4* bb = (const float4*)(b2 + (size_t)e2 * DDIM);
  float4 a0 = ya0[t], a1 = ya1[t], c0 = yb0[t], c1 = yb1[t];
  float4 pa = ba[t], pb = bb[t];
  float4 o;
  o.x = g1 * (a0.x + a1.x + pa.x) + g2 * (c0.x + c1.x + pb.x);
  o.y = g1 * (a0.y + a1.y + pa.y) + g2 * (c0.y + c1.y + pb.y);
  o.z = g1 * (a0.z + a1.z + pa.z) + g2 * (c0.z + c1.z + pb.z);
  o.w = g1 * (a0.w + a1.w + pa.w) + g2 * (c0.w + c1.w + pb.w);
  out4[(size_t)n * (DDIM / 4) + t] = o;
}

// ---------------------------------------------------------------- launch
extern "C" void kernel_launch(void* const* d_in, const int* in_sizes, int n_in,
                              void* d_out, int out_size, void* d_ws, size_t ws_size,
                              hipStream_t stream) {
  const float* x  = (const float*)d_in[0];
  const float* Wg = (const float*)d_in[1];
  const float* W1 = (const float*)d_in[2];
  const float* b1 = (const float*)d_in[3];
  const float* W2 = (const float*)d_in[4];
  const float* b2 = (const float*)d_in[5];
  float* out = (float*)d_out;

  char* ws = (char*)d_ws;
  size_t off = 0;
  auto alloc = [&](size_t bytes) -> void* {
    void* p = (void*)(ws + off);
    off += (bytes + 255) & ~(size_t)255;
    return p;
  };
  bf16_t* xbf   = (bf16_t*)alloc((size_t)NTOK * DDIM * 2);
  bf16_t* wt1   = (bf16_t*)alloc((size_t)NEXP * FDIM * DDIM * 2);  // dead after gemm1
  bf16_t* wt2   = (bf16_t*)alloc((size_t)NEXP * DDIM * FDIM * 2);
  bf16_t* H     = (bf16_t*)alloc((size_t)HROWS * FDIM * 2);
  int*    tokL  = (int*)alloc((size_t)NEXP * CAP * 4);
  int*    pairE = (int*)alloc((size_t)NPAIR * 4);
  int*    pairS = (int*)alloc((size_t)NPAIR * 4);
  float*  pairG = (float*)alloc((size_t)NPAIR * 4);
  int*    cnts  = (int*)alloc(64);
  int*    offs  = (int*)alloc(64);
  int*    blkE  = (int*)alloc(MAXB * 4);
  int*    blkS  = (int*)alloc(MAXB * 4);
  if (off > ws_size) return;

  // Y0/Y1 alias wt1 (64 MiB): wt1 consumed by gemm1 before gemm2 (same stream).
  float* Y0 = (float*)wt1;
  float* Y1 = Y0 + (size_t)8192 * DDIM;

  hipMemsetAsync(cnts, 0, 64, stream);
  prep_kernel<<<13312, 256, 0, stream>>>(W1, W2, x, Wg, wt1, wt2, xbf, tokL, cnts,
                                         pairE, pairS, pairG);
  offs_kernel<<<1, 64, 0, stream>>>(cnts, offs, blkE, blkS);
  gemm1_kernel<<<dim3(FDIM / 128, MAXB), 256, 0, stream>>>(
      xbf, wt1, b1, tokL, cnts, offs, blkE, blkS, H);
  gemm2_kernel<<<dim3(DDIM / 128, MAXB * 2), 256, 0, stream>>>(
      H, wt2, cnts, offs, blkE, blkS, Y0, Y1);
  combine_kernel<<<NTOK, 256, 0, stream>>>(Y0, Y1, b2, pairE, pairS, pairG, offs,
                                           (float4*)out);
}